// Round 9
// baseline (147.596 us; speedup 1.0000x reference)
//
#include <hip/hip_runtime.h>

// S=4096, D=64.  out = (t * floor(t*rr)/R) @ V,  t = (QK^T*8) * dropout_keep/0.9
// R21 = R20 resubmitted (R8 bench died at container level, no verdict; kernel
// re-audited: no barriers/fences to deadlock, direct-load addresses verified
// bit-identical to R16's staged path).
// R20: NO LDS STAGING, NO BARRIERS. Kbf/VTbf/Q are L2-resident (2MB total,
// re-read by all ib-blocks) — staging them through LDS was pure overhead
// (guide common-mistake #7): the DMA, vmcnt drains and ALL barriers existed
// only to publish LDS tiles. Fragment loads go straight to global:
//   bK = Kbf[(j0+cs*16+n16)*D + ks*32+quad*8]   (16B, L2-hit)
//   bV = VTbf[(ds*16+n16)*S + j0+ksj*32+quad*8] (16B, L2-hit)
// (identical data to the old kb/vb staging by the DMA's own address math).
// Waves are now fully independent straight-line code; latency hidden by
// occupancy (NCHUNK=16 -> 1024 blocks, 4 blocks/CU, 16 waves/CU) instead of
// hand pipelining. Ud is the only HBM stream. Swapped QK^T + lane-local mask
// + in-register bpermute P transpose kept verbatim from R16.

#define S 4096
#define D 64
#define NCHUNK 16             // grid = 64 i-blocks * 16 chunks = 1024 blocks
#define JCHUNK (S / NCHUNK)   // 256
#define JT 128
#define NTILES (JCHUNK / JT)  // 2
#define KSCALE (8.0f / 0.9f)

typedef float f32x4 __attribute__((ext_vector_type(4)));
typedef short s16x8 __attribute__((ext_vector_type(8)));
typedef unsigned short u16x4 __attribute__((ext_vector_type(4)));
typedef int i32x4 __attribute__((ext_vector_type(4)));

__device__ inline unsigned short f2bf(float f) {
    union { float f; unsigned u; } v; v.f = f;
    unsigned r = v.u + 0x7fffu + ((v.u >> 16) & 1u);
    return (unsigned short)(r >> 16);
}

__device__ inline unsigned cvt_pk_bf16(float lo, float hi) {
    unsigned r;
    asm("v_cvt_pk_bf16_f32 %0, %1, %2" : "=v"(r) : "v"(lo), "v"(hi));
    return r;   // [15:0]=bf16(lo), [31:16]=bf16(hi)
}

// ---- prep: K->bf16*KSCALE (blocks 0..255), V->V^T (256..319) ----
__global__ void prep_all(const float* __restrict__ Kf,
                         const float* __restrict__ V,
                         short* __restrict__ Kbf,
                         short* __restrict__ VTbf,
                         int* __restrict__ sumr) {
    __shared__ short tile[64 * 68];
    const int b   = blockIdx.x;
    const int tid = threadIdx.x;
    if (b == 0 && tid == 0) *sumr = 0;

    if (b < 256) {
        const int k = b * 256 + tid;                 // 65536 float4 slots
        float4 v = ((const float4*)Kf)[k];
        u16x4 o; o[0] = f2bf(v.x * KSCALE); o[1] = f2bf(v.y * KSCALE);
                 o[2] = f2bf(v.z * KSCALE); o[3] = f2bf(v.w * KSCALE);
        ((u16x4*)Kbf)[k] = o;
    } else {
        const int j0 = (b - 256) * 64;
#pragma unroll
        for (int it = 0; it < 4; ++it) {
            const int f4 = tid + it * 256;
            const int row = f4 >> 4, c4 = (f4 & 15) * 4;
            float4 v = *(const float4*)&V[(size_t)(j0 + row) * D + c4];
            tile[(c4 + 0) * 68 + row] = (short)f2bf(v.x);
            tile[(c4 + 1) * 68 + row] = (short)f2bf(v.y);
            tile[(c4 + 2) * 68 + row] = (short)f2bf(v.z);
            tile[(c4 + 3) * 68 + row] = (short)f2bf(v.w);
        }
        __syncthreads();
#pragma unroll
        for (int it = 0; it < 4; ++it) {
            const int f4 = tid + it * 256;
            const int d = f4 >> 4, o4 = (f4 & 15) * 4;
            u16x4 w = *(const u16x4*)&tile[d * 68 + o4];
            *(u16x4*)&VTbf[(size_t)d * S + j0 + o4] = w;
        }
    }
}

// ---- main: barrier-free, LDS-free (except 16B lsum reduction) ----
__launch_bounds__(256, 4)
__global__ void fused_main(const float* __restrict__ Qf,
                           const short* __restrict__ Kbf,
                           const short* __restrict__ VTbf,
                           const float* __restrict__ Ud,
                           const float* __restrict__ RR,
                           float* __restrict__ Opart,            // [NCHUNK][S][D]
                           int* __restrict__ sumr)
{
    __shared__ int red[4];

    const int tid  = threadIdx.x;
    const int w    = tid >> 6;
    const int lane = tid & 63;
    const int quad = lane >> 4;
    const int n16  = lane & 15;

    const int ib  = blockIdx.x & 63;
    const int ic  = blockIdx.x >> 6;     // 0..NCHUNK-1
    const int i0w = ib * 64 + w * 16;
    const int jbase = ic * JCHUNK;

    // Q fragment: f32 direct (L2-resident), convert in-reg (RNE = f2bf)
    s16x8 aQ[2];
#pragma unroll
    for (int ks = 0; ks < 2; ++ks) {
        const float* qp = &Qf[(size_t)(i0w + n16) * D + ks * 32 + quad * 8];
        f32x4 qa = *(const f32x4*)qp;
        f32x4 qb = *(const f32x4*)(qp + 4);
        i32x4 aw;
        aw[0] = (int)cvt_pk_bf16(qa[0], qa[1]);
        aw[1] = (int)cvt_pk_bf16(qa[2], qa[3]);
        aw[2] = (int)cvt_pk_bf16(qb[0], qb[1]);
        aw[3] = (int)cvt_pk_bf16(qb[2], qb[3]);
        __builtin_memcpy(&aQ[ks], &aw, 16);
    }
    const float rrn = RR[i0w + n16];
    const float* uln = Ud + (size_t)(i0w + n16) * S + quad * 4;

    f32x4 accO[4];
#pragma unroll
    for (int ds = 0; ds < 4; ++ds) accO[ds] = (f32x4){0.f, 0.f, 0.f, 0.f};
    float lsum = 0.f;

    const int pbase = (32 * ((lane >> 4) & 1) + n16) * 4;

#pragma unroll
    for (int jt = 0; jt < NTILES; ++jt) {
        const int j0 = jbase + jt * JT;

        // (1) u loads: the only HBM stream (8 x 16B per lane)
        float4 un[8];
#pragma unroll
        for (int c = 0; c < 8; ++c)
            un[c] = *(const float4*)&uln[j0 + c * 16];
        unsigned um = 0;
#pragma unroll
        for (int c = 0; c < 8; ++c) {
            um |= (un[c].x >= 0.1f ? 1u : 0u) << (c * 4 + 0);
            um |= (un[c].y >= 0.1f ? 1u : 0u) << (c * 4 + 1);
            um |= (un[c].z >= 0.1f ? 1u : 0u) << (c * 4 + 2);
            um |= (un[c].w >= 0.1f ? 1u : 0u) << (c * 4 + 3);
        }

        // (2) swapped QK^T with DIRECT global K fragments (L2-hit) + epilogue
        unsigned pkw[16];
#pragma unroll
        for (int cs = 0; cs < 8; ++cs) {
            f32x4 acc = (f32x4){0.f, 0.f, 0.f, 0.f};
#pragma unroll
            for (int ks = 0; ks < 2; ++ks) {
                s16x8 bK = *(const s16x8*)&Kbf[(size_t)(j0 + cs * 16 + n16) * D + ks * 32 + quad * 8];
                acc = __builtin_amdgcn_mfma_f32_16x16x32_bf16(bK, aQ[ks], acc, 0, 0, 0);
            }
            float vv[4];
#pragma unroll
            for (int rg = 0; rg < 4; ++rg) {
                const float t = ((um >> (cs * 4 + rg)) & 1u) ? acc[rg] : 0.0f;
                const float r = floorf(t * rrn);
                lsum += r;
                vv[rg] = t * r;
            }
            pkw[cs * 2]     = cvt_pk_bf16(vv[0], vv[1]);
            pkw[cs * 2 + 1] = cvt_pk_bf16(vv[2], vv[3]);
        }

        // (3) in-register P transpose (bpermute) + PV with DIRECT global V^T
#pragma unroll
        for (int ksj = 0; ksj < 4; ++ksj) {
            i32x4 aw;
#pragma unroll
            for (int widx = 0; widx < 4; ++widx) {
                const int addr = pbase + (widx >> 1) * 64;
                const int lo = __builtin_amdgcn_ds_bpermute(addr, (int)pkw[ksj * 4 + (widx & 1)]);
                const int hi = __builtin_amdgcn_ds_bpermute(addr, (int)pkw[ksj * 4 + 2 + (widx & 1)]);
                aw[widx] = (lane >= 32) ? hi : lo;
            }
            s16x8 aP;
            __builtin_memcpy(&aP, &aw, 16);
#pragma unroll
            for (int ds = 0; ds < 4; ++ds) {
                s16x8 bV = *(const s16x8*)&VTbf[(size_t)(ds * 16 + n16) * S + j0 + ksj * 32 + quad * 8];
                accO[ds] = __builtin_amdgcn_mfma_f32_16x16x32_bf16(aP, bV, accO[ds], 0, 0, 0);
            }
        }
    }

    // deterministic partial stores (full 64B segments)
    float* op = Opart + (size_t)ic * S * D;
#pragma unroll
    for (int ds = 0; ds < 4; ++ds) {
        const int d = ds * 16 + n16;
#pragma unroll
        for (int rg = 0; rg < 4; ++rg) {
            const int i = i0w + quad * 4 + rg;
            op[(size_t)i * D + d] = accO[ds][rg];
        }
    }

    // sum(r): wave shuffle -> LDS -> one int atomic per block
    for (int off = 32; off; off >>= 1) lsum += __shfl_down(lsum, off);
    if (lane == 0) red[w] = (int)lsum;
    __syncthreads();
    if (tid == 0) atomicAdd(sumr, red[0] + red[1] + red[2] + red[3]);
}

// ---- reduce partials over NCHUNK + apply 1/R ----
__global__ void reduce_out(const float* __restrict__ Opart,
                           const int* __restrict__ sumr,
                           float* __restrict__ out) {
    const int idx = blockIdx.x * 256 + threadIdx.x;   // 65536 float4 groups
    const float invR = 1.0f / (float)(*sumr);         // |R| < 2^24: exact
    float sx = 0.f, sy = 0.f, sz = 0.f, sw = 0.f;
#pragma unroll
    for (int c = 0; c < NCHUNK; ++c) {
        const float4 v = ((const float4*)(Opart + (size_t)c * S * D))[idx];
        sx += v.x; sy += v.y; sz += v.z; sw += v.w;
    }
    float4 o; o.x = sx * invR; o.y = sy * invR; o.z = sz * invR; o.w = sw * invR;
    ((float4*)out)[idx] = o;
}

extern "C" void kernel_launch(void* const* d_in, const int* in_sizes, int n_in,
                              void* d_out, int out_size, void* d_ws, size_t ws_size,
                              hipStream_t stream) {
    (void)in_sizes; (void)n_in; (void)out_size; (void)ws_size;
    const float* Q  = (const float*)d_in[0];
    const float* Kf = (const float*)d_in[1];
    const float* V  = (const float*)d_in[2];
    const float* Ud = (const float*)d_in[3];
    const float* RR = (const float*)d_in[4];
    float* out = (float*)d_out;

    // ws layout: Opart 16MB | Kbf 512KB | VTbf 512KB | sumr  (ws is 256MB)
    char* ws = (char*)d_ws;
    float* Opart = (float*)ws;                                  // 16 MB
    short* Kbf  = (short*)(ws + (16u << 20));
    short* VTbf = (short*)(ws + (16u << 20) + (512u << 10));
    int*   sumr = (int*)  (ws + (16u << 20) + (1024u << 10));

    prep_all<<<dim3(320), dim3(256), 0, stream>>>(Kf, V, Kbf, VTbf, sumr);
    fused_main<<<dim3(64 * NCHUNK), dim3(256), 0, stream>>>(
        Q, Kbf, VTbf, Ud, RR, Opart, sumr);
    reduce_out<<<dim3(256), dim3(256), 0, stream>>>(Opart, sumr, out);
}

// Round 10
// 125.306 us; speedup vs baseline: 1.1779x; 1.1779x over previous
//
#include <hip/hip_runtime.h>
#include <stdint.h>

// S=4096, D=64.  out = (t * floor(t*rr)/R) @ V,  t = (QK^T*8) * dropout_keep/0.9
// R22 = R16 base (best total 120.9; kb/vb dbuf, 1 barrier/tile, swapped QK^T,
// lane-local mask, in-reg bpermute P transpose, Opart+reduce_out) with the
// Ud STREAM MADE CONTIGUOUS. R21 proved K/V need LDS staging (direct L2 loads
// in the MFMA chain: 33->55us). R16's u pattern was 64B segments @16KB stride
// (lane reads cols quad*4+c*16) — worst-case DRAM granularity on the ONLY HBM
// stream. Now lane (quad,n16) loads 128B contiguous (cols quad*32..+31), so
// each row contributes one 512B segment. Bits are then routed to the lanes
// that consume them with 4 ds_bpermutes: pack byte b = nibble(un[b]) |
// nibble(un[b+4])<<4; um = sum_qs byte[my_quad](from lane qs*16+n16) << 8qs.
// Resulting bit index = 4cs+rg — identical to the old um consumption.
// Q stays direct-f32 + in-reg cvt (prep 320 blocks, verified R18/R21).

#define S 4096
#define D 64
#define NCHUNK 8              // grid = 64 i-blocks * 8 chunks = 512 blocks
#define JCHUNK (S / NCHUNK)   // 512
#define JT 128
#define NTILES (JCHUNK / JT)  // 4
#define KSCALE (8.0f / 0.9f)

typedef float f32x4 __attribute__((ext_vector_type(4)));
typedef short s16x8 __attribute__((ext_vector_type(8)));
typedef unsigned short u16x4 __attribute__((ext_vector_type(4)));
typedef int i32x4 __attribute__((ext_vector_type(4)));
typedef const __attribute__((address_space(1))) unsigned g_u32;
typedef __attribute__((address_space(3))) unsigned lds_u32;

__device__ inline unsigned short f2bf(float f) {
    union { float f; unsigned u; } v; v.f = f;
    unsigned r = v.u + 0x7fffu + ((v.u >> 16) & 1u);
    return (unsigned short)(r >> 16);
}

__device__ inline unsigned cvt_pk_bf16(float lo, float hi) {
    unsigned r;
    asm("v_cvt_pk_bf16_f32 %0, %1, %2" : "=v"(r) : "v"(lo), "v"(hi));
    return r;   // [15:0]=bf16(lo), [31:16]=bf16(hi)
}

// ---- prep: K->bf16*KSCALE (blocks 0..255), V->V^T (256..319) ----
__global__ void prep_all(const float* __restrict__ Kf,
                         const float* __restrict__ V,
                         short* __restrict__ Kbf,
                         short* __restrict__ VTbf,
                         int* __restrict__ sumr) {
    __shared__ short tile[64 * 68];
    const int b   = blockIdx.x;
    const int tid = threadIdx.x;
    if (b == 0 && tid == 0) *sumr = 0;

    if (b < 256) {
        const int k = b * 256 + tid;                 // 65536 float4 slots
        float4 v = ((const float4*)Kf)[k];
        u16x4 o; o[0] = f2bf(v.x * KSCALE); o[1] = f2bf(v.y * KSCALE);
                 o[2] = f2bf(v.z * KSCALE); o[3] = f2bf(v.w * KSCALE);
        ((u16x4*)Kbf)[k] = o;
    } else {
        const int j0 = (b - 256) * 64;
#pragma unroll
        for (int it = 0; it < 4; ++it) {
            const int f4 = tid + it * 256;
            const int row = f4 >> 4, c4 = (f4 & 15) * 4;
            float4 v = *(const float4*)&V[(size_t)(j0 + row) * D + c4];
            tile[(c4 + 0) * 68 + row] = (short)f2bf(v.x);
            tile[(c4 + 1) * 68 + row] = (short)f2bf(v.y);
            tile[(c4 + 2) * 68 + row] = (short)f2bf(v.z);
            tile[(c4 + 3) * 68 + row] = (short)f2bf(v.w);
        }
        __syncthreads();
#pragma unroll
        for (int it = 0; it < 4; ++it) {
            const int f4 = tid + it * 256;
            const int d = f4 >> 4, o4 = (f4 & 15) * 4;
            u16x4 w = *(const u16x4*)&tile[d * 68 + o4];
            *(u16x4*)&VTbf[(size_t)d * S + j0 + o4] = w;
        }
    }
}

// ---- main ----
__launch_bounds__(256, 2)
__global__ void fused_main(const float* __restrict__ Qf,
                           const short* __restrict__ Kbf,
                           const short* __restrict__ VTbf,
                           const float* __restrict__ Ud,
                           const float* __restrict__ RR,
                           float* __restrict__ Opart,            // [NCHUNK][S][D]
                           int* __restrict__ sumr)
{
    __shared__ short kb[2][16 * 512];    // K tile 128x64, fragment-major (frag=1KB)
    __shared__ short vb[2][16 * 512];    // V^T tile 64x128, fragment-major, DBUF
    __shared__ int red[4];

    const int tid  = threadIdx.x;
    const int w    = tid >> 6;
    const int lane = tid & 63;
    const int quad = lane >> 4;
    const int n16  = lane & 15;

    const int ib  = blockIdx.x & 63;
    const int ic  = blockIdx.x >> 6;     // 0..NCHUNK-1
    const int i0w = ib * 64 + w * 16;
    const int jbase = ic * JCHUNK;

    // Q fragment: f32 direct (L2-resident), convert in-reg (RNE = f2bf)
    s16x8 aQ[2];
#pragma unroll
    for (int ks = 0; ks < 2; ++ks) {
        const float* qp = &Qf[(size_t)(i0w + n16) * D + ks * 32 + quad * 8];
        f32x4 qa = *(const f32x4*)qp;
        f32x4 qb = *(const f32x4*)(qp + 4);
        i32x4 aw;
        aw[0] = (int)cvt_pk_bf16(qa[0], qa[1]);
        aw[1] = (int)cvt_pk_bf16(qa[2], qa[3]);
        aw[2] = (int)cvt_pk_bf16(qb[0], qb[1]);
        aw[3] = (int)cvt_pk_bf16(qb[2], qb[3]);
        __builtin_memcpy(&aQ[ks], &aw, 16);
    }
    const float rrn = RR[i0w + n16];

    // dropout row for THIS lane (i = i0w + n16), CONTIGUOUS 128B window:
    // cols quad*32 .. quad*32+31 of each tile (512B/row per wave)
    const float* uln = Ud + (size_t)(i0w + n16) * S + quad * 32;

    f32x4 accO[4];
#pragma unroll
    for (int ds = 0; ds < 4; ++ds) accO[ds] = (f32x4){0.f, 0.f, 0.f, 0.f};

    float lsum = 0.f;
    float4 un[8];                        // u(t): row n16, cols quad*32 + c*4 +0..3
    unsigned um;                         // 32 keep-bits, bit index 4cs+rg

    // ---- prologue: K0,V0 DMA + u0 loads; drain K0/V0; barrier ----
    {
#pragma unroll
        for (int p = 0; p < 4; ++p) {
            const int e = w * 4 + p;
            __builtin_amdgcn_global_load_lds(
                (g_u32*)&Kbf[(size_t)(jbase + (e >> 1) * 16 + n16) * D + (e & 1) * 32 + quad * 8],
                (lds_u32*)&kb[0][e * 512], 16, 0, 0);
        }
#pragma unroll
        for (int p = 0; p < 4; ++p) {
            const int e = w * 4 + p;
            __builtin_amdgcn_global_load_lds(
                (g_u32*)&VTbf[(size_t)((e & 3) * 16 + n16) * S + jbase + (e >> 2) * 32 + quad * 8],
                (lds_u32*)&vb[0][e * 512], 16, 0, 0);
        }
#pragma unroll
        for (int c = 0; c < 8; ++c)
            un[c] = *(const float4*)&uln[jbase + c * 4];
        __asm__ volatile("s_waitcnt vmcnt(8)" ::: "memory");   // K0,V0 landed; u0 may fly
        __builtin_amdgcn_s_barrier();
        __asm__ volatile("" ::: "memory");
    }

#pragma unroll
    for (int jt = 0; jt < NTILES; ++jt) {
        const int bu = jt & 1;
        const int nb = bu ^ 1;
        const bool last = (jt + 1 == NTILES);

        // (a) issue NEXT tile K/V DMA (into nb; safe: end-of-prev barrier passed)
        if (!last) {
            const int j1 = jbase + (jt + 1) * JT;
#pragma unroll
            for (int p = 0; p < 4; ++p) {
                const int e = w * 4 + p;
                __builtin_amdgcn_global_load_lds(
                    (g_u32*)&Kbf[(size_t)(j1 + (e >> 1) * 16 + n16) * D + (e & 1) * 32 + quad * 8],
                    (lds_u32*)&kb[nb][e * 512], 16, 0, 0);
            }
#pragma unroll
            for (int p = 0; p < 4; ++p) {
                const int e = w * 4 + p;
                __builtin_amdgcn_global_load_lds(
                    (g_u32*)&VTbf[(size_t)((e & 3) * 16 + n16) * S + j1 + (e >> 2) * 32 + quad * 8],
                    (lds_u32*)&vb[nb][e * 512], 16, 0, 0);
            }
        }

        // (b) pack u(t): bit (c,e) belongs to (cs=2quad+(c>>2), qt=c&3, rg=e).
        //     byte b = nibble(un[b]) | nibble(un[b+4])<<4, at position 8b.
        //     Then 4 bpermutes route byte[my_quad] from lanes qs*16+n16 ->
        //     um bit index 8qs+4half+rg = 4cs+rg (same consumption as before).
        {
            unsigned m = 0;
#pragma unroll
            for (int c = 0; c < 8; ++c) {
                unsigned nib = (un[c].x >= 0.1f ? 1u : 0u)
                             | (un[c].y >= 0.1f ? 2u : 0u)
                             | (un[c].z >= 0.1f ? 4u : 0u)
                             | (un[c].w >= 0.1f ? 8u : 0u);
                m |= nib << (8 * (c & 3) + 4 * (c >> 2));
            }
            unsigned r = 0;
#pragma unroll
            for (int qs = 0; qs < 4; ++qs) {
                const int v = __builtin_amdgcn_ds_bpermute((qs * 16 + n16) * 4, (int)m);
                r |= (((unsigned)v >> (8 * quad)) & 0xFFu) << (8 * qs);
            }
            um = r;
        }
        if (!last) {
            const int j1 = jbase + (jt + 1) * JT;
#pragma unroll
            for (int c = 0; c < 8; ++c)
                un[c] = *(const float4*)&uln[j1 + c * 4];
        }

        // (c) swapped QK^T + lane-local epilogue: acc[rg] = P[i=n16][j=16cs+4quad+rg]
        unsigned pkw[16];                // bf16-pair words: pkw[c*2+m] = (val[2m],val[2m+1])
#pragma unroll
        for (int cs = 0; cs < 8; ++cs) {
            f32x4 acc = (f32x4){0.f, 0.f, 0.f, 0.f};
#pragma unroll
            for (int ks = 0; ks < 2; ++ks) {
                s16x8 bK = *(const s16x8*)&kb[bu][(cs * 2 + ks) * 512 + lane * 8];
                acc = __builtin_amdgcn_mfma_f32_16x16x32_bf16(bK, aQ[ks], acc, 0, 0, 0);
            }
            float vv[4];
#pragma unroll
            for (int rg = 0; rg < 4; ++rg) {
                const float t = ((um >> (cs * 4 + rg)) & 1u) ? acc[rg] : 0.0f;
                const float r = floorf(t * rrn);
                lsum += r;
                vv[rg] = t * r;
            }
            pkw[cs * 2]     = cvt_pk_bf16(vv[0], vv[1]);
            pkw[cs * 2 + 1] = cvt_pk_bf16(vv[2], vv[3]);
        }

        // (e) in-register P transpose (bpermute within n16-columns) + PV.
        // target aP word widx of ksj = pk-word [4ksj + 2*(q>=2) + (widx&1)]
        // of lane (2*(q&1) + (widx>>1))*16 + n16.
        const int pbase = (32 * ((lane >> 4) & 1) + n16) * 4;
#pragma unroll
        for (int ksj = 0; ksj < 4; ++ksj) {
            i32x4 aw;
#pragma unroll
            for (int widx = 0; widx < 4; ++widx) {
                const int addr = pbase + (widx >> 1) * 64;
                const int lo = __builtin_amdgcn_ds_bpermute(addr, (int)pkw[ksj * 4 + (widx & 1)]);
                const int hi = __builtin_amdgcn_ds_bpermute(addr, (int)pkw[ksj * 4 + 2 + (widx & 1)]);
                aw[widx] = (lane >= 32) ? hi : lo;
            }
            s16x8 aP;
            __builtin_memcpy(&aP, &aw, 16);
#pragma unroll
            for (int ds = 0; ds < 4; ++ds) {
                s16x8 bV = *(const s16x8*)&vb[bu][(ksj * 4 + ds) * 512 + lane * 8];
                accO[ds] = __builtin_amdgcn_mfma_f32_16x16x32_bf16(aP, bV, accO[ds], 0, 0, 0);
            }
        }

        // (f) end-of-tile: drain K/V(t+1) (u(t+1) 8 youngest may fly); barrier
        //     guards both landing (for t+1 reads) and bu-buffer reuse (t+2 DMA).
        if (!last) {
            __asm__ volatile("s_waitcnt vmcnt(8)" ::: "memory");
            __builtin_amdgcn_s_barrier();
            __asm__ volatile("" ::: "memory");
        }
    }

    // deterministic partial stores (full 64B segments)
    float* op = Opart + (size_t)ic * S * D;
#pragma unroll
    for (int ds = 0; ds < 4; ++ds) {
        const int d = ds * 16 + n16;
#pragma unroll
        for (int rg = 0; rg < 4; ++rg) {
            const int i = i0w + quad * 4 + rg;
            op[(size_t)i * D + d] = accO[ds][rg];
        }
    }

    // sum(r): wave shuffle -> LDS -> one int atomic per block
    for (int off = 32; off; off >>= 1) lsum += __shfl_down(lsum, off);
    if (lane == 0) red[w] = (int)lsum;
    __syncthreads();
    if (tid == 0) atomicAdd(sumr, red[0] + red[1] + red[2] + red[3]);
}

// ---- reduce partials over NCHUNK + apply 1/R ----
__global__ void reduce_out(const float* __restrict__ Opart,
                           const int* __restrict__ sumr,
                           float* __restrict__ out) {
    const int idx = blockIdx.x * 256 + threadIdx.x;   // 65536 float4 groups
    const float invR = 1.0f / (float)(*sumr);         // |R| < 2^24: exact
    float sx = 0.f, sy = 0.f, sz = 0.f, sw = 0.f;
#pragma unroll
    for (int c = 0; c < NCHUNK; ++c) {
        const float4 v = ((const float4*)(Opart + (size_t)c * S * D))[idx];
        sx += v.x; sy += v.y; sz += v.z; sw += v.w;
    }
    float4 o; o.x = sx * invR; o.y = sy * invR; o.z = sz * invR; o.w = sw * invR;
    ((float4*)out)[idx] = o;
}

extern "C" void kernel_launch(void* const* d_in, const int* in_sizes, int n_in,
                              void* d_out, int out_size, void* d_ws, size_t ws_size,
                              hipStream_t stream) {
    (void)in_sizes; (void)n_in; (void)out_size; (void)ws_size;
    const float* Q  = (const float*)d_in[0];
    const float* Kf = (const float*)d_in[1];
    const float* V  = (const float*)d_in[2];
    const float* Ud = (const float*)d_in[3];
    const float* RR = (const float*)d_in[4];
    float* out = (float*)d_out;

    // ws layout: Opart 8MB | Kbf 512KB | VTbf 512KB | sumr
    char* ws = (char*)d_ws;
    float* Opart = (float*)ws;                                  // 8 MB
    short* Kbf  = (short*)(ws + (8u << 20));
    short* VTbf = (short*)(ws + (8u << 20) + (512u << 10));
    int*   sumr = (int*)  (ws + (8u << 20) + (1024u << 10));

    prep_all<<<dim3(320), dim3(256), 0, stream>>>(Kf, V, Kbf, VTbf, sumr);
    fused_main<<<dim3(64 * NCHUNK), dim3(256), 0, stream>>>(
        Q, Kbf, VTbf, Ud, RR, Opart, sumr);
    reduce_out<<<dim3(256), dim3(256), 0, stream>>>(Opart, sumr, out);
}